// Round 1
// baseline (1669.287 us; speedup 1.0000x reference)
//
#include <hip/hip_runtime.h>
#include <math.h>

#define NF 128      // hidden dim H
#define FIN 256     // in features

// ---------------- CSR construction ----------------

__global__ void k_deg(const int* __restrict__ row, int* __restrict__ cnt, int E) {
    int e = blockIdx.x * 256 + threadIdx.x;
    if (e < E) atomicAdd(&cnt[row[e]], 1);
}

__global__ __launch_bounds__(1024) void k_scan1(const int* __restrict__ cnt,
                                                int* __restrict__ incl,
                                                int* __restrict__ part, int n) {
    __shared__ int sm[1024];
    const int t = threadIdx.x;
    const int base = blockIdx.x * 1024;
    int v = (base + t < n) ? cnt[base + t] : 0;
    sm[t] = v;
    __syncthreads();
    for (int off = 1; off < 1024; off <<= 1) {
        int u = (t >= off) ? sm[t - off] : 0;
        __syncthreads();
        sm[t] += u;
        __syncthreads();
    }
    if (base + t < n) incl[base + t] = sm[t];
    if (t == 1023) part[blockIdx.x] = sm[1023];
}

__global__ void k_scan2(int* part, int np) {   // in-place exclusive scan, np <= 128
    __shared__ int sm[128];
    const int t = threadIdx.x;
    int v = (t < np) ? part[t] : 0;
    sm[t] = v;
    __syncthreads();
    for (int off = 1; off < 128; off <<= 1) {
        int u = (t >= off) ? sm[t - off] : 0;
        __syncthreads();
        sm[t] += u;
        __syncthreads();
    }
    if (t < np) part[t] = sm[t] - v;
}

__global__ void k_rowptr(const int* __restrict__ cnt, const int* __restrict__ incl,
                         const int* __restrict__ part, int* __restrict__ rowp,
                         int* __restrict__ curs, float* __restrict__ dinv,
                         float* __restrict__ nself, int n) {
    int i = blockIdx.x * 256 + threadIdx.x;
    if (i >= n) return;
    int start = incl[i] - cnt[i] + part[i >> 10];
    rowp[i] = start;
    curs[i] = start;
    float deg = (float)cnt[i] + 1.0f;
    dinv[i]  = rsqrtf(deg);
    nself[i] = 1.0f / deg;
}

__global__ void k_fill(const int* __restrict__ row, const int* __restrict__ col,
                       const float* __restrict__ dinv, int* __restrict__ curs,
                       int* __restrict__ ccol, float* __restrict__ cw, int E) {
    int e = blockIdx.x * 256 + threadIdx.x;
    if (e >= E) return;
    int r = row[e], c = col[e];
    int p = atomicAdd(&curs[r], 1);
    ccol[p] = c;
    cw[p]   = dinv[r] * dinv[c];
}

// ---------------- SpMM + support epilogue ----------------
// One block (128 threads) per destination node; lane = feature.
// S[n] = 0.9 * (sum_e w_e * h[col_e] + nself[n]*h[n]) + 0.1 * h0[n]

__global__ __launch_bounds__(128) void k_spmm(const float* __restrict__ h,
                                              const float* __restrict__ h0,
                                              const int* __restrict__ rowp,
                                              const int* __restrict__ endp,
                                              const int* __restrict__ ccol,
                                              const float* __restrict__ cw,
                                              const float* __restrict__ nself,
                                              float* __restrict__ S, int n) {
    const int node = blockIdx.x;
    if (node >= n) return;
    const int f = threadIdx.x;
    float acc = nself[node] * h[(size_t)node * NF + f];
    int p = rowp[node];
    const int e = endp[node];
    #pragma unroll 4
    for (; p < e; ++p) {
        acc += cw[p] * h[(size_t)ccol[p] * NF + f];
    }
    S[(size_t)node * NF + f] = 0.9f * acc + 0.1f * h0[(size_t)node * NF + f];
}

// ---------------- dense GEMM, C[N,128] = A[N,K] @ B[K,128] (+ epilogue) ----------------
// MODE 0: C = acc + bias (X = bias[128])
// MODE 1: C = relu(theta*acc + (1-theta)*X[r,c])   (X = S, in-place safe)
// MODE 2: C = theta*acc + (1-theta)*X[r,c]
// 64 rows x 128 cols per block of 256 threads; thread = 8 rows x 4 cols.

template<int K, int MODE>
__global__ __launch_bounds__(256) void k_gemm(const float* __restrict__ A,
                                              const float* __restrict__ B,
                                              const float* __restrict__ X,
                                              float* __restrict__ C,
                                              int nrows, float theta) {
    __shared__ float As[64 * 32];
    __shared__ float Bs[32 * NF];
    const int tid = threadIdx.x;
    const int tr = tid >> 5;        // 0..7  (8 row-groups)
    const int tc = tid & 31;        // 0..31 (col quad)
    const int rowbase = blockIdx.x * 64;

    float4 acc[8];
    #pragma unroll
    for (int i = 0; i < 8; i++) acc[i] = make_float4(0.f, 0.f, 0.f, 0.f);

    for (int k0 = 0; k0 < K; k0 += 32) {
        // stage A tile 64x32
        #pragma unroll
        for (int p = 0; p < 2; p++) {
            int i  = tid + p * 256;          // float4 index 0..511
            int r  = i >> 3;
            int kq = (i & 7) << 2;
            int gr = rowbase + r;
            float4 v = make_float4(0.f, 0.f, 0.f, 0.f);
            if (gr < nrows) v = *(const float4*)(A + (size_t)gr * K + k0 + kq);
            *(float4*)(As + r * 32 + kq) = v;
        }
        // stage B tile 32x128
        #pragma unroll
        for (int p = 0; p < 4; p++) {
            int i  = tid + p * 256;          // float4 index 0..1023
            int br = i >> 5;
            int bc = (i & 31) << 2;
            *(float4*)(Bs + br * NF + bc) = *(const float4*)(B + (size_t)(k0 + br) * NF + bc);
        }
        __syncthreads();
        #pragma unroll
        for (int kk4 = 0; kk4 < 8; kk4++) {
            float4 av[8];
            #pragma unroll
            for (int i = 0; i < 8; i++)
                av[i] = *(const float4*)(As + (tr * 8 + i) * 32 + kk4 * 4);
            #pragma unroll
            for (int j = 0; j < 4; j++) {
                float4 b = *(const float4*)(Bs + (kk4 * 4 + j) * NF + (tc << 2));
                #pragma unroll
                for (int i = 0; i < 8; i++) {
                    float a = (j == 0) ? av[i].x : (j == 1) ? av[i].y : (j == 2) ? av[i].z : av[i].w;
                    acc[i].x = fmaf(a, b.x, acc[i].x);
                    acc[i].y = fmaf(a, b.y, acc[i].y);
                    acc[i].z = fmaf(a, b.z, acc[i].z);
                    acc[i].w = fmaf(a, b.w, acc[i].w);
                }
            }
        }
        __syncthreads();
    }

    const float om = 1.0f - theta;
    #pragma unroll
    for (int i = 0; i < 8; i++) {
        int gr = rowbase + tr * 8 + i;
        if (gr >= nrows) continue;
        float4 o = acc[i];
        if (MODE == 0) {
            float4 bb = *(const float4*)(X + (tc << 2));
            o.x += bb.x; o.y += bb.y; o.z += bb.z; o.w += bb.w;
        } else {
            float4 s = *(const float4*)(X + (size_t)gr * NF + (tc << 2));
            o.x = theta * o.x + om * s.x;
            o.y = theta * o.y + om * s.y;
            o.z = theta * o.z + om * s.z;
            o.w = theta * o.w + om * s.w;
            if (MODE == 1) {
                o.x = fmaxf(o.x, 0.f); o.y = fmaxf(o.y, 0.f);
                o.z = fmaxf(o.z, 0.f); o.w = fmaxf(o.w, 0.f);
            }
        }
        *(float4*)(C + (size_t)gr * NF + (tc << 2)) = o;
    }
}

// ---------------- host launch ----------------

extern "C" void kernel_launch(void* const* d_in, const int* in_sizes, int n_in,
                              void* d_out, int out_size, void* d_ws, size_t ws_size,
                              hipStream_t stream) {
    const float* x   = (const float*)d_in[0];
    const float* fcw = (const float*)d_in[1];
    const float* fcb = (const float*)d_in[2];
    const float* Ws  = (const float*)d_in[3];
    const int*   ei  = (const int*)d_in[4];
    const int N = in_sizes[0] / FIN;
    const int E = in_sizes[4] / 2;
    const int* row = ei;
    const int* col = ei + E;
    float* out = (float*)d_out;

    char* base = (char*)d_ws;
    size_t off = 0;
    auto alloc = [&](size_t b) -> char* {
        char* p = base + off;
        off += (b + 255) & ~(size_t)255;
        return p;
    };
    float* h0    = (float*)alloc((size_t)N * NF * sizeof(float));
    float* bufA  = (float*)alloc((size_t)N * NF * sizeof(float));
    int*   ccol  = (int*)alloc((size_t)E * sizeof(int));
    float* cw    = (float*)alloc((size_t)E * sizeof(float));
    int*   cnt   = (int*)alloc((size_t)N * sizeof(int));
    int*   incl  = (int*)alloc((size_t)N * sizeof(int));
    int*   rowp  = (int*)alloc((size_t)N * sizeof(int));
    int*   curs  = (int*)alloc((size_t)N * sizeof(int));
    float* dinv  = (float*)alloc((size_t)N * sizeof(float));
    float* nself = (float*)alloc((size_t)N * sizeof(float));
    int*   part  = (int*)alloc(1024);
    if (off > ws_size) return;   // ws too small: fail loudly (no corruption)

    hipMemsetAsync(cnt, 0, (size_t)N * sizeof(int), stream);
    const int eb = (E + 255) / 256;
    k_deg<<<eb, 256, 0, stream>>>(row, cnt, E);
    const int nch = (N + 1023) / 1024;                 // 98 <= 128
    k_scan1<<<nch, 1024, 0, stream>>>(cnt, incl, part, N);
    k_scan2<<<1, 128, 0, stream>>>(part, nch);
    k_rowptr<<<(N + 255) / 256, 256, 0, stream>>>(cnt, incl, part, rowp, curs, dinv, nself, N);
    k_fill<<<eb, 256, 0, stream>>>(row, col, dinv, curs, ccol, cw, E);

    const int gb = (N + 63) / 64;
    // h0 = x @ fc_w + fc_b
    k_gemm<FIN, 0><<<gb, 256, 0, stream>>>(x, fcw, fcb, h0, N, 0.f);

    const float thetas[4] = { logf(1.5f), logf(1.25f), logf(0.5f / 3.f + 1.f), logf(1.125f) };
    float* hcur = h0;
    for (int l = 1; l <= 4; l++) {
        float* S = (l == 2 || l == 4) ? out : bufA;   // ping-pong; layers 2 & 4 land in d_out
        k_spmm<<<N, 128, 0, stream>>>(hcur, h0, rowp, curs, ccol, cw, nself, S, N);
        const float* W = Ws + (size_t)(l - 1) * NF * NF;
        if (l < 4)
            k_gemm<NF, 1><<<gb, 256, 0, stream>>>(S, W, S, S, N, thetas[l - 1]);
        else
            k_gemm<NF, 2><<<gb, 256, 0, stream>>>(S, W, S, S, N, thetas[3]);
        hcur = S;
    }
}